// Round 9
// baseline (198.881 us; speedup 1.0000x reference)
//
#include <hip/hip_runtime.h>

// Residual VQ (L=4, K=4096, C=256, N=4096) — bf16 screen + exact-candidate refine.
// Proven 2-kernel-per-level structure. Gemm tile widened to 128x256 (grid 512):
// A-tile staged once per K-step, two B-tiles; per-block fixed costs amortized 2x.
// Screen error bound eps = 0.004*||r||; margin M = 0.012*||r|| >= 3*eps.
// Overflow paths degrade deterministically to coalesced full exact scan.

// ws layout (float units):
#define OFF_AS   0          // N x 256 bf16      = 524288 floats
#define OFF_BS   524288     // L*K x 256 bf16    = 2097152 floats
#define OFF_R    2621440    // N x C fp32        = 1048576
#define OFF_INV  3670016    // L x K             = 16384
#define OFF_PV   3686400    // N x 16            = 65536 (allocated 131072)
#define OFF_RN   3817472    // N                 = 4096
#define OFF_CNT  3821568    // N (int)           = 4096
#define OFF_CAND 3825664    // N x 256 (int)     = 1048576
#define OFF_CVAL 4874240    // N x 256           = 1048576
#define OFF_SSQ  5922816    // L x N             = 16384
// total 5939200 floats ~ 23.8 MB

#define BETA 0.25f
#define EPSN 1e-12f
#define CAP 256
#define SLC 16              // LDS candidate slots per row per 256-col slice
#define OVF (1 << 20)       // overflow marker
#define MARGIN 0.012f
#define NEGINF -3.0e38f

typedef __attribute__((ext_vector_type(8))) short short8;
typedef __attribute__((ext_vector_type(4))) short short4v;
typedef __attribute__((ext_vector_type(4))) float f32x4;

__device__ __forceinline__ unsigned short f2bf(float x) {
  unsigned u = __float_as_uint(x);
  unsigned r = (u + 0x7fffu + ((u >> 16) & 1u)) >> 16;
  return (unsigned short)r;
}

__device__ __forceinline__ void gload16(const void* g, void* s) {
  __builtin_amdgcn_global_load_lds(
      (const __attribute__((address_space(1))) unsigned int*)g,
      (__attribute__((address_space(3))) unsigned int*)s, 16, 0, 0);
}

// ---- merged prep: blocks 0..2047 codebook (norm + bf16 B); 2048..2559 rows ----
__global__ __launch_bounds__(256) void k_prep(const float* __restrict__ z,
                                              const float* __restrict__ cb,
                                              float* __restrict__ r,
                                              unsigned short* __restrict__ AS,
                                              float* __restrict__ rnorm,
                                              int* __restrict__ cnt,
                                              float* __restrict__ inv,
                                              unsigned short* __restrict__ BS) {
  __shared__ __align__(16) char psm[9472];
  int tid = threadIdx.x;
  int w = tid >> 6, lane = tid & 63;
  if (blockIdx.x < 2048) {
    // ---- codebook part: 8 rows per block ----
    float (*t)[260] = (float(*)[260])psm;
    float* sinvs = (float*)(psm + 8320);
    int r0 = blockIdx.x * 8;
#pragma unroll
    for (int p = 0; p < 2; ++p) {
      int idx = p * 1024 + tid * 4;
      float4 v = *(const float4*)(cb + (size_t)r0 * 256 + idx);
      int row = idx >> 8, c = idx & 255;
      *(float4*)&t[row][c] = v;
    }
    __syncthreads();
#pragma unroll
    for (int rr = 0; rr < 2; ++rr) {
      int row = w * 2 + rr;
      float4 v = *(const float4*)&t[row][lane * 4];
      float s = v.x * v.x + v.y * v.y + v.z * v.z + v.w * v.w;
#pragma unroll
      for (int off = 32; off; off >>= 1) s += __shfl_xor(s, off);
      if (lane == 0) sinvs[row] = 1.0f / fmaxf(sqrtf(s), EPSN);
    }
    __syncthreads();
    if (tid < 8) inv[r0 + tid] = sinvs[tid];
#pragma unroll
    for (int p = 0; p < 2; ++p) {
      int idx = p * 1024 + tid * 4;
      int row = idx >> 8, c = idx & 255;
      float sc = sinvs[row];
      short4v s4;
      s4[0] = (short)f2bf(t[row][c + 0] * sc);
      s4[1] = (short)f2bf(t[row][c + 1] * sc);
      s4[2] = (short)f2bf(t[row][c + 2] * sc);
      s4[3] = (short)f2bf(t[row][c + 3] * sc);
      *(short4v*)(BS + (size_t)r0 * 256 + idx) = s4;
    }
  } else {
    // ---- rows part: transpose z -> r + bf16 A + norms + counter reset ----
    float (*t)[9] = (float(*)[9])psm;
    float* wpart = (float*)(psm + 9216);   // [4][8]
    int n0 = (blockIdx.x - 2048) * 8;
    int b = n0 >> 10, hw0 = n0 & 1023;
#pragma unroll
    for (int p = 0; p < 8; ++p) {
      int c = p * 32 + (tid >> 3), h = tid & 7;
      t[c][h] = z[((b * 256 + c) << 10) + hw0 + h];
    }
    __syncthreads();
#pragma unroll
    for (int h = 0; h < 8; ++h) {
      float v = t[tid][h];
      float s = v * v;
#pragma unroll
      for (int off = 32; off; off >>= 1) s += __shfl_xor(s, off);
      if (lane == 0) wpart[w * 8 + h] = s;
    }
    __syncthreads();
    if (tid < 8) {
      float tot = (wpart[0 * 8 + tid] + wpart[1 * 8 + tid]) +
                  (wpart[2 * 8 + tid] + wpart[3 * 8 + tid]);
      rnorm[n0 + tid] = sqrtf(tot);
      cnt[n0 + tid] = 0;
    }
#pragma unroll
    for (int h = 0; h < 8; ++h) {
      float v = t[tid][h];
      r[(n0 + h) * 256 + tid] = v;
      AS[(n0 + h) * 256 + tid] = f2bf(v);
    }
  }
}

// ---- bf16 screen GEMM (128x256 tile, grid 512) + slice max + candidates ----
// A staged once per K-step, shared by two 128-col B tiles. Epilogue aliased.
__global__ __launch_bounds__(256) void k_gemm_argmax(
    const unsigned short* __restrict__ AS, const unsigned short* __restrict__ BS,
    float* __restrict__ pval, const float* __restrict__ rnorm,
    int* __restrict__ cnt, int* __restrict__ cand, float* __restrict__ cval) {
  __shared__ __align__(16) char sm[49152];
  unsigned short* lA  = (unsigned short*)sm;            // 16 KB (K-loop)
  unsigned short* lB0 = (unsigned short*)(sm + 16384);  // 16 KB
  unsigned short* lB1 = (unsigned short*)(sm + 32768);  // 16 KB
  float* sv    = (float*)sm;                            // [4][64] (epilogue)
  float* scomb = (float*)(sm + 1024);                   // [2][64]
  float* rn_s  = (float*)(sm + 1536);
  int*   lcnt  = (int*)(sm + 2048);
  int*   lck   = (int*)(sm + 2560);                     // [128][SLC] 8 KB
  float* lcv   = (float*)(sm + 10752);                  // 8 KB (ends 18944)

  int bid = blockIdx.x;
  int wg = (bid & 7) * 64 + (bid >> 3);   // XCD swizzle (512 % 8 == 0)
  int bm = wg >> 4, bn = wg & 15;
  int mbase = bm * 128, nbase = bn * 256;
  int tid = threadIdx.x;
  int wid = tid >> 6, ln = tid & 63;
  int wr = wid >> 1, wc = wid & 1;
  int grp = ln >> 4, li = ln & 15;

  f32x4 acc0[4][4], acc1[4][4];
#pragma unroll
  for (int i = 0; i < 4; ++i)
#pragma unroll
    for (int j = 0; j < 4; ++j) {
      acc0[i][j] = (f32x4){0.f, 0.f, 0.f, 0.f};
      acc1[i][j] = (f32x4){0.f, 0.f, 0.f, 0.f};
    }

  for (int ks = 0; ks < 4; ++ks) {
    __syncthreads();
    int k0 = ks * 64;
#pragma unroll
    for (int i = 0; i < 4; ++i) {
      int idx = i * 256 + tid;
      int row = idx >> 3, cc = idx & 7;
      int src = cc ^ (row & 7);
      gload16(AS + ((mbase + row) << 8) + k0 + src * 8, ((char*)lA) + idx * 16);
    }
#pragma unroll
    for (int i = 0; i < 4; ++i) {
      int idx = i * 256 + tid;
      int row = idx >> 3, cc = idx & 7;
      int src = cc ^ (row & 7);
      gload16(BS + ((nbase + row) << 8) + k0 + src * 8, ((char*)lB0) + idx * 16);
    }
#pragma unroll
    for (int i = 0; i < 4; ++i) {
      int idx = i * 256 + tid;
      int row = idx >> 3, cc = idx & 7;
      int src = cc ^ (row & 7);
      gload16(BS + ((nbase + 128 + row) << 8) + k0 + src * 8, ((char*)lB1) + idx * 16);
    }
    __syncthreads();
#pragma unroll
    for (int kk = 0; kk < 2; ++kk) {
      short8 b0[4], b1[4];
#pragma unroll
      for (int ni = 0; ni < 4; ++ni) {
        int row = wc * 64 + ni * 16 + li;
        int cc = kk * 4 + grp;
        int off = row * 128 + (cc ^ (row & 7)) * 16;
        b0[ni] = *(const short8*)(((const char*)lB0) + off);
        b1[ni] = *(const short8*)(((const char*)lB1) + off);
      }
#pragma unroll
      for (int mi = 0; mi < 4; ++mi) {
        int row = wr * 64 + mi * 16 + li;
        int cc = kk * 4 + grp;
        short8 a = *(const short8*)(((const char*)lA) + row * 128 + (cc ^ (row & 7)) * 16);
#pragma unroll
        for (int ni = 0; ni < 4; ++ni) {
          acc0[mi][ni] = __builtin_amdgcn_mfma_f32_16x16x32_bf16(a, b0[ni], acc0[mi][ni], 0, 0, 0);
          acc1[mi][ni] = __builtin_amdgcn_mfma_f32_16x16x32_bf16(a, b1[ni], acc1[mi][ni], 0, 0, 0);
        }
      }
    }
  }

  // per-wave 256-col slice max per row — into registers first (LDS still = tiles)
  float redv[4][4];
#pragma unroll
  for (int mi = 0; mi < 4; ++mi) {
#pragma unroll
    for (int reg = 0; reg < 4; ++reg) {
      float v = fmaxf(acc0[mi][0][reg], acc1[mi][0][reg]);
#pragma unroll
      for (int ni = 1; ni < 4; ++ni)
        v = fmaxf(v, fmaxf(acc0[mi][ni][reg], acc1[mi][ni][reg]));
#pragma unroll
      for (int off = 1; off < 16; off <<= 1) v = fmaxf(v, __shfl_xor(v, off));
      redv[mi][reg] = v;
    }
  }
  __syncthreads();   // all tile reads done -> safe to alias epilogue arrays
#pragma unroll
  for (int mi = 0; mi < 4; ++mi)
#pragma unroll
    for (int reg = 0; reg < 4; ++reg)
      if (li == 0) sv[(wr * 2 + wc) * 64 + mi * 16 + grp * 4 + reg] = redv[mi][reg];
  __syncthreads();
  if (tid < 128) {
    int wr2 = tid >> 6, r64 = tid & 63;
    float m = fmaxf(sv[(wr2 * 2 + 0) * 64 + r64], sv[(wr2 * 2 + 1) * 64 + r64]);
    int n = mbase + wr2 * 64 + r64;
    pval[n * 16 + bn] = m;
    scomb[wr2 * 64 + r64] = m;
    rn_s[wr2 * 64 + r64] = rnorm[n];
    lcnt[tid] = 0;
  }
  __syncthreads();
  // candidate collection into per-row LDS buffers (LDS atomics only)
#pragma unroll
  for (int mi = 0; mi < 4; ++mi) {
#pragma unroll
    for (int reg = 0; reg < 4; ++reg) {
      int rl = mi * 16 + grp * 4 + reg;
      float thr = scomb[wr * 64 + rl] - MARGIN * rn_s[wr * 64 + rl];
      int rloc = wr * 64 + rl;
#pragma unroll
      for (int ni = 0; ni < 4; ++ni) {
        float v0 = acc0[mi][ni][reg];
        if (v0 >= thr) {
          int pos = atomicAdd(&lcnt[rloc], 1);
          if (pos < SLC) {
            lck[rloc * SLC + pos] = nbase + wc * 64 + ni * 16 + li;
            lcv[rloc * SLC + pos] = v0;
          }
        }
        float v1 = acc1[mi][ni][reg];
        if (v1 >= thr) {
          int pos = atomicAdd(&lcnt[rloc], 1);
          if (pos < SLC) {
            lck[rloc * SLC + pos] = nbase + 128 + wc * 64 + ni * 16 + li;
            lcv[rloc * SLC + pos] = v1;
          }
        }
      }
    }
  }
  __syncthreads();
  // write-out: one global atomic per row (parallel across 128 threads)
  if (tid < 128) {
    int rloc = tid;
    int n = mbase + rloc;
    int raw = lcnt[rloc];
    int lc = raw < SLC ? raw : SLC;
    int add = raw > SLC ? (lc + OVF) : lc;
    if (add > 0) {
      int base = atomicAdd(&cnt[n], add);
      for (int j = 0; j < lc; ++j) {
        int pos = base + j;
        if (pos < CAP) {
          cand[n * CAP + pos] = lck[rloc * SLC + j];
          cval[n * CAP + pos] = lcv[rloc * SLC + j];
        }
      }
    }
  }
}

// ---- fused: filter vs global max -> wave-parallel exact dots -> argmax
//      -> residual update + next A split + norms + counter reset ----
__global__ __launch_bounds__(256) void k_refine_update(
    const float* __restrict__ cb, const float* __restrict__ inv,
    float* __restrict__ r, const float* __restrict__ pval,
    float* __restrict__ rnorm, int* __restrict__ cnt,
    const int* __restrict__ cand, const float* __restrict__ cval,
    unsigned short* __restrict__ AS, float* __restrict__ ssq,
    float* __restrict__ out_idx, int l) {
  __shared__ float rrow[256];
  __shared__ float gm_s;
  __shared__ int list[CAP];
  __shared__ int lcnt;
  __shared__ float wbv[4];
  __shared__ int wbk[4];
  __shared__ int sbk;
  __shared__ float wsum[4];

  int n = blockIdx.x, tid = threadIdx.x;
  int w = tid >> 6, lane = tid & 63;
  rrow[tid] = r[(n << 8) + tid];
  if (tid == 0) lcnt = 0;
  if (tid < 64) {
    float v = (lane < 16) ? pval[n * 16 + lane] : NEGINF;
#pragma unroll
    for (int off = 1; off < 16; off <<= 1) v = fmaxf(v, __shfl_xor(v, off));
    if (tid == 0) gm_s = v;
  }
  __syncthreads();

  int c = cnt[n];
  const float* cbl = cb + ((size_t)l << 20);
  const float* invl = inv + (l << 12);
  float bv = NEGINF; int bk = 0x7fffffff;
  float4 rv4 = *(const float4*)(rrow + lane * 4);

  if (c <= CAP) {
    float thr = gm_s - MARGIN * rnorm[n];
    if (tid < c) {
      float v = cval[n * CAP + tid];
      if (v >= thr) { int p = atomicAdd(&lcnt, 1); list[p] = cand[n * CAP + tid]; }
    }
    __syncthreads();
    int m = lcnt;
    for (int j = w; j < m; j += 4) {          // wave-parallel exact dots
      int k = list[j];
      float4 e4 = *(const float4*)(cbl + ((size_t)k << 8) + lane * 4);
      float p = rv4.x * e4.x + rv4.y * e4.y + rv4.z * e4.z + rv4.w * e4.w;
#pragma unroll
      for (int off = 32; off; off >>= 1) p += __shfl_xor(p, off);
      float s = p * invl[k];
      if (s > bv || (s == bv && k < bk)) { bv = s; bk = k; }
    }
  } else {
    __syncthreads();                           // keep barrier count uniform
    // coalesced full exact scan: wave w handles rows 4*kk + w
    for (int kk = 0; kk < 1024; ++kk) {
      int k = kk * 4 + w;
      float4 e4 = *(const float4*)(cbl + ((size_t)k << 8) + lane * 4);
      float p = rv4.x * e4.x + rv4.y * e4.y + rv4.z * e4.z + rv4.w * e4.w;
#pragma unroll
      for (int off = 32; off; off >>= 1) p += __shfl_xor(p, off);
      float s = p * invl[k];
      if (s > bv || (s == bv && k < bk)) { bv = s; bk = k; }
    }
  }
  if (lane == 0) { wbv[w] = bv; wbk[w] = bk; }
  __syncthreads();
  if (tid == 0) {
    float v0 = wbv[0]; int i0 = wbk[0];
#pragma unroll
    for (int ww = 1; ww < 4; ++ww) {
      float ov = wbv[ww]; int oi = wbk[ww];
      if (ov > v0 || (ov == v0 && oi < i0)) { v0 = ov; i0 = oi; }
    }
    sbk = i0;
    out_idx[(l << 12) + n] = (float)i0;
  }
  __syncthreads();

  // ---- residual update + next-level A split (A/rnorm/cnt dead at l==3) ----
  int ii = sbk;
  float e = cbl[((size_t)ii << 8) + tid];
  float rvv = rrow[tid] - e;
  r[(n << 8) + tid] = rvv;
  if (l != 3) AS[(n << 8) + tid] = f2bf(rvv);
  float sq = rvv * rvv;
#pragma unroll
  for (int off = 32; off; off >>= 1) sq += __shfl_xor(sq, off);
  if (lane == 0) wsum[w] = sq;
  __syncthreads();
  if (tid == 0) {
    float tot = (wsum[0] + wsum[1]) + (wsum[2] + wsum[3]);
    ssq[(l << 12) + n] = tot;
    if (l != 3) { rnorm[n] = sqrtf(tot); cnt[n] = 0; }
  }
}

// ---- z_q_st = z - residual_final (blocks 0..1023); qloss (block 1024) ----
__global__ __launch_bounds__(256) void k_writeq_qloss(const float* __restrict__ z,
                                                      const float* __restrict__ r,
                                                      const float* __restrict__ ssq,
                                                      float* __restrict__ out) {
  int tid = threadIdx.x;
  if (blockIdx.x == 1024) {
    __shared__ float wsumq[4];
    float q = 0.f;
    for (int l = 0; l < 4; ++l) {
      float p = 0.f;
#pragma unroll
      for (int i = 0; i < 16; ++i) p += ssq[l * 4096 + i * 256 + tid];
      int lane = tid & 63, w = tid >> 6;
#pragma unroll
      for (int off = 32; off; off >>= 1) p += __shfl_xor(p, off);
      if (lane == 0) wsumq[w] = p;
      __syncthreads();
      float tot = (wsumq[0] + wsumq[1]) + (wsumq[2] + wsumq[3]);
      q += BETA * (tot * (1.0f / (4096.0f * 256.0f)));
      __syncthreads();
    }
    if (tid == 0) out[1048576 + 16384] = q;
    return;
  }
  __shared__ float t[32][33];
  int id = blockIdx.x;
  int b = id >> 8; int rem = id & 255; int ct = rem >> 5; int ht = rem & 31;
  int c0 = ct * 32, h0 = ht * 32;
  int col = tid & 31, row0 = tid >> 5;
#pragma unroll
  for (int p = 0; p < 4; ++p) {
    int row = row0 + p * 8;
    t[row][col] = r[(b * 1024 + h0 + row) * 256 + c0 + col];
  }
  __syncthreads();
#pragma unroll
  for (int p = 0; p < 4; ++p) {
    int row = row0 + p * 8;
    int o = ((b * 256 + c0 + row) << 10) + h0 + col;
    out[o] = z[o] - t[col][row];
  }
}

extern "C" void kernel_launch(void* const* d_in, const int* in_sizes, int n_in,
                              void* d_out, int out_size, void* d_ws, size_t ws_size,
                              hipStream_t stream) {
  const float* z  = (const float*)d_in[0];
  const float* cb = (const float*)d_in[1];
  float* out = (float*)d_out;
  float* ws  = (float*)d_ws;

  unsigned short* AS = (unsigned short*)(ws + OFF_AS);
  unsigned short* BS = (unsigned short*)(ws + OFF_BS);
  float* r     = ws + OFF_R;
  float* inv   = ws + OFF_INV;
  float* pval  = ws + OFF_PV;
  float* rnorm = ws + OFF_RN;
  int*   cnt   = (int*)(ws + OFF_CNT);
  int*   cand  = (int*)(ws + OFF_CAND);
  float* cval  = ws + OFF_CVAL;
  float* ssq   = ws + OFF_SSQ;

  k_prep<<<2560, 256, 0, stream>>>(z, cb, r, AS, rnorm, cnt, inv, BS);
  for (int l = 0; l < 4; ++l) {
    k_gemm_argmax<<<512, 256, 0, stream>>>(AS, BS + (size_t)l * 4096 * 256,
                                           pval, rnorm, cnt, cand, cval);
    k_refine_update<<<4096, 256, 0, stream>>>(cb, inv, r, pval, rnorm, cnt,
                                              cand, cval, AS, ssq,
                                              out + 1048576, l);
  }
  k_writeq_qloss<<<1025, 256, 0, stream>>>(z, r, ssq, out);
}

// Round 10
// 164.603 us; speedup vs baseline: 1.2082x; 1.2082x over previous
//
#include <hip/hip_runtime.h>

// Residual VQ (L=4, K=4096, C=256, N=4096) — bf16 screen + exact-candidate refine.
// Round-8 gemm config (128x128, 4 blocks/CU) — verified fastest.
// Refine rewritten wave-per-row (grid 1024, no block barriers).
// Screen error bound eps = 0.004*||r||; margin M = 0.012*||r|| >= 3*eps.
// Overflow paths degrade deterministically to full exact scan (wave-serial).

// ws layout (float units):
#define OFF_AS   0          // N x 256 bf16      = 524288 floats
#define OFF_BS   524288     // L*K x 256 bf16    = 2097152 floats
#define OFF_R    2621440    // N x C fp32        = 1048576
#define OFF_INV  3670016    // L x K             = 16384
#define OFF_PV   3686400    // N x 32            = 131072
#define OFF_RN   3817472    // N                 = 4096
#define OFF_CNT  3821568    // N (int)           = 4096
#define OFF_CAND 3825664    // N x 256 (int)     = 1048576
#define OFF_CVAL 4874240    // N x 256           = 1048576
#define OFF_SSQ  5922816    // L x N             = 16384
// total 5939200 floats ~ 23.8 MB

#define BETA 0.25f
#define EPSN 1e-12f
#define CAP 256
#define SLC 16              // LDS candidate slots per row per 128-col slice
#define OVF (1 << 20)       // overflow marker
#define MARGIN 0.012f
#define NEGINF -3.0e38f

typedef __attribute__((ext_vector_type(8))) short short8;
typedef __attribute__((ext_vector_type(4))) short short4v;
typedef __attribute__((ext_vector_type(4))) float f32x4;

__device__ __forceinline__ unsigned short f2bf(float x) {
  unsigned u = __float_as_uint(x);
  unsigned r = (u + 0x7fffu + ((u >> 16) & 1u)) >> 16;
  return (unsigned short)r;
}

__device__ __forceinline__ void gload16(const void* g, void* s) {
  __builtin_amdgcn_global_load_lds(
      (const __attribute__((address_space(1))) unsigned int*)g,
      (__attribute__((address_space(3))) unsigned int*)s, 16, 0, 0);
}

// ---- merged prep: blocks 0..2047 codebook (norm + bf16 B); 2048..2559 rows ----
__global__ __launch_bounds__(256) void k_prep(const float* __restrict__ z,
                                              const float* __restrict__ cb,
                                              float* __restrict__ r,
                                              unsigned short* __restrict__ AS,
                                              float* __restrict__ rnorm,
                                              int* __restrict__ cnt,
                                              float* __restrict__ inv,
                                              unsigned short* __restrict__ BS) {
  __shared__ __align__(16) char psm[9472];
  int tid = threadIdx.x;
  int w = tid >> 6, lane = tid & 63;
  if (blockIdx.x < 2048) {
    // ---- codebook part: 8 rows per block ----
    float (*t)[260] = (float(*)[260])psm;
    float* sinvs = (float*)(psm + 8320);
    int r0 = blockIdx.x * 8;
#pragma unroll
    for (int p = 0; p < 2; ++p) {
      int idx = p * 1024 + tid * 4;
      float4 v = *(const float4*)(cb + (size_t)r0 * 256 + idx);
      int row = idx >> 8, c = idx & 255;
      *(float4*)&t[row][c] = v;
    }
    __syncthreads();
#pragma unroll
    for (int rr = 0; rr < 2; ++rr) {
      int row = w * 2 + rr;
      float4 v = *(const float4*)&t[row][lane * 4];
      float s = v.x * v.x + v.y * v.y + v.z * v.z + v.w * v.w;
#pragma unroll
      for (int off = 32; off; off >>= 1) s += __shfl_xor(s, off);
      if (lane == 0) sinvs[row] = 1.0f / fmaxf(sqrtf(s), EPSN);
    }
    __syncthreads();
    if (tid < 8) inv[r0 + tid] = sinvs[tid];
#pragma unroll
    for (int p = 0; p < 2; ++p) {
      int idx = p * 1024 + tid * 4;
      int row = idx >> 8, c = idx & 255;
      float sc = sinvs[row];
      short4v s4;
      s4[0] = (short)f2bf(t[row][c + 0] * sc);
      s4[1] = (short)f2bf(t[row][c + 1] * sc);
      s4[2] = (short)f2bf(t[row][c + 2] * sc);
      s4[3] = (short)f2bf(t[row][c + 3] * sc);
      *(short4v*)(BS + (size_t)r0 * 256 + idx) = s4;
    }
  } else {
    // ---- rows part: transpose z -> r + bf16 A + norms + counter reset ----
    float (*t)[9] = (float(*)[9])psm;
    float* wpart = (float*)(psm + 9216);   // [4][8]
    int n0 = (blockIdx.x - 2048) * 8;
    int b = n0 >> 10, hw0 = n0 & 1023;
#pragma unroll
    for (int p = 0; p < 8; ++p) {
      int c = p * 32 + (tid >> 3), h = tid & 7;
      t[c][h] = z[((b * 256 + c) << 10) + hw0 + h];
    }
    __syncthreads();
#pragma unroll
    for (int h = 0; h < 8; ++h) {
      float v = t[tid][h];
      float s = v * v;
#pragma unroll
      for (int off = 32; off; off >>= 1) s += __shfl_xor(s, off);
      if (lane == 0) wpart[w * 8 + h] = s;
    }
    __syncthreads();
    if (tid < 8) {
      float tot = (wpart[0 * 8 + tid] + wpart[1 * 8 + tid]) +
                  (wpart[2 * 8 + tid] + wpart[3 * 8 + tid]);
      rnorm[n0 + tid] = sqrtf(tot);
      cnt[n0 + tid] = 0;
    }
#pragma unroll
    for (int h = 0; h < 8; ++h) {
      float v = t[tid][h];
      r[(n0 + h) * 256 + tid] = v;
      AS[(n0 + h) * 256 + tid] = f2bf(v);
    }
  }
}

// ---- bf16 screen GEMM (128x128 tile) + slice max + LDS-compacted candidates ----
// Epilogue LDS aliased onto lA/lB (dead after K-loop): total 32.8 KB.
__global__ __launch_bounds__(256) void k_gemm_argmax(
    const unsigned short* __restrict__ AS, const unsigned short* __restrict__ BS,
    float* __restrict__ pval, const float* __restrict__ rnorm,
    int* __restrict__ cnt, int* __restrict__ cand, float* __restrict__ cval) {
  __shared__ __align__(16) char sm[32768];
  unsigned short* lA = (unsigned short*)sm;             // 16384 B (K-loop)
  unsigned short* lB = (unsigned short*)(sm + 16384);   // 16384 B (K-loop)
  float* sv    = (float*)sm;                            // [4][64] 1024 B (epilogue)
  float* scomb = (float*)(sm + 1024);                   // [2][64] 512 B
  float* rn_s  = (float*)(sm + 1536);                   // 512 B
  int*   lcnt  = (int*)(sm + 2048);                     // 512 B
  int*   lck   = (int*)(sm + 2560);                     // [128][SLC] 8192 B
  float* lcv   = (float*)(sm + 10752);                  // 8192 B (ends 18944)

  int bid = blockIdx.x;
  int wg = (bid & 7) * 128 + (bid >> 3);   // XCD swizzle (1024 % 8 == 0)
  int bm = wg >> 5, bn = wg & 31;
  int mbase = bm * 128, nbase = bn * 128;
  int tid = threadIdx.x;
  int wid = tid >> 6, ln = tid & 63;
  int wr = wid >> 1, wc = wid & 1;
  int grp = ln >> 4, li = ln & 15;

  f32x4 acc[4][4];
#pragma unroll
  for (int i = 0; i < 4; ++i)
#pragma unroll
    for (int j = 0; j < 4; ++j) acc[i][j] = (f32x4){0.f, 0.f, 0.f, 0.f};

  for (int ks = 0; ks < 4; ++ks) {
    __syncthreads();
    int k0 = ks * 64;
#pragma unroll
    for (int i = 0; i < 4; ++i) {
      int idx = i * 256 + tid;
      int row = idx >> 3, cc = idx & 7;
      int src = cc ^ (row & 7);
      gload16(AS + ((mbase + row) << 8) + k0 + src * 8, ((char*)lA) + idx * 16);
    }
#pragma unroll
    for (int i = 0; i < 4; ++i) {
      int idx = i * 256 + tid;
      int row = idx >> 3, cc = idx & 7;
      int src = cc ^ (row & 7);
      gload16(BS + ((nbase + row) << 8) + k0 + src * 8, ((char*)lB) + idx * 16);
    }
    __syncthreads();
#pragma unroll
    for (int kk = 0; kk < 2; ++kk) {
      short8 b[4];
#pragma unroll
      for (int ni = 0; ni < 4; ++ni) {
        int row = wc * 64 + ni * 16 + li;
        int cc = kk * 4 + grp;
        b[ni] = *(const short8*)(((const char*)lB) + row * 128 + (cc ^ (row & 7)) * 16);
      }
#pragma unroll
      for (int mi = 0; mi < 4; ++mi) {
        int row = wr * 64 + mi * 16 + li;
        int cc = kk * 4 + grp;
        short8 a = *(const short8*)(((const char*)lA) + row * 128 + (cc ^ (row & 7)) * 16);
#pragma unroll
        for (int ni = 0; ni < 4; ++ni)
          acc[mi][ni] = __builtin_amdgcn_mfma_f32_16x16x32_bf16(a, b[ni], acc[mi][ni], 0, 0, 0);
      }
    }
  }

  // per-wave 64-col slice max per row — into registers first (LDS still = tiles)
  float redv[4][4];
#pragma unroll
  for (int mi = 0; mi < 4; ++mi) {
#pragma unroll
    for (int reg = 0; reg < 4; ++reg) {
      float v = acc[mi][0][reg];
#pragma unroll
      for (int ni = 1; ni < 4; ++ni) v = fmaxf(v, acc[mi][ni][reg]);
#pragma unroll
      for (int off = 1; off < 16; off <<= 1) v = fmaxf(v, __shfl_xor(v, off));
      redv[mi][reg] = v;
    }
  }
  __syncthreads();   // all tile reads done -> safe to alias epilogue arrays
#pragma unroll
  for (int mi = 0; mi < 4; ++mi)
#pragma unroll
    for (int reg = 0; reg < 4; ++reg)
      if (li == 0) sv[(wr * 2 + wc) * 64 + mi * 16 + grp * 4 + reg] = redv[mi][reg];
  __syncthreads();
  if (tid < 128) {
    int wr2 = tid >> 6, r64 = tid & 63;
    float m = fmaxf(sv[(wr2 * 2 + 0) * 64 + r64], sv[(wr2 * 2 + 1) * 64 + r64]);
    int n = mbase + wr2 * 64 + r64;
    pval[n * 32 + bn] = m;
    scomb[wr2 * 64 + r64] = m;
    rn_s[wr2 * 64 + r64] = rnorm[n];
    lcnt[tid] = 0;
  }
  __syncthreads();
  // candidate collection into per-row LDS buffers (LDS atomics only)
#pragma unroll
  for (int mi = 0; mi < 4; ++mi) {
#pragma unroll
    for (int reg = 0; reg < 4; ++reg) {
      int rl = mi * 16 + grp * 4 + reg;
      float thr = scomb[wr * 64 + rl] - MARGIN * rn_s[wr * 64 + rl];
      int rloc = wr * 64 + rl;
#pragma unroll
      for (int ni = 0; ni < 4; ++ni) {
        float v = acc[mi][ni][reg];
        if (v >= thr) {
          int pos = atomicAdd(&lcnt[rloc], 1);
          if (pos < SLC) {
            lck[rloc * SLC + pos] = nbase + wc * 64 + ni * 16 + li;
            lcv[rloc * SLC + pos] = v;
          }
        }
      }
    }
  }
  __syncthreads();
  // write-out: one global atomic per row (parallel across 128 threads)
  if (tid < 128) {
    int rloc = tid;
    int n = mbase + rloc;
    int raw = lcnt[rloc];
    int lc = raw < SLC ? raw : SLC;
    int add = raw > SLC ? (lc + OVF) : lc;
    if (add > 0) {
      int base = atomicAdd(&cnt[n], add);
      for (int j = 0; j < lc; ++j) {
        int pos = base + j;
        if (pos < CAP) {
          cand[n * CAP + pos] = lck[rloc * SLC + j];
          cval[n * CAP + pos] = lcv[rloc * SLC + j];
        }
      }
    }
  }
}

// ---- wave-per-row refine: filter vs global max -> exact dots -> argmax
//      -> residual update + next A split. Grid 1024, 4 rows/block, NO barriers.
__global__ __launch_bounds__(256) void k_refine_update(
    const float* __restrict__ cb, const float* __restrict__ inv,
    float* __restrict__ r, const float* __restrict__ pval,
    float* __restrict__ rnorm, int* __restrict__ cnt,
    const int* __restrict__ cand, const float* __restrict__ cval,
    unsigned short* __restrict__ AS, float* __restrict__ ssq,
    float* __restrict__ out_idx, int l) {
  __shared__ int lists[4][CAP];
  __shared__ int lcnts[4];
  int tid = threadIdx.x, w = tid >> 6, lane = tid & 63;
  int n = blockIdx.x * 4 + w;
  const float* cbl = cb + ((size_t)l << 20);
  const float* invl = inv + (l << 12);

  float4 rv4 = *(const float4*)(r + ((size_t)n << 8) + lane * 4);

  // global screened max: lanes 0..31 reduce pval slices
  float v = (lane < 32) ? pval[n * 32 + lane] : NEGINF;
#pragma unroll
  for (int off = 16; off; off >>= 1) v = fmaxf(v, __shfl_xor(v, off));
  float gm = __shfl(v, 0);

  if (lane == 0) lcnts[w] = 0;   // per-wave LDS, in-order DS pipeline
  int c = cnt[n];
  float bv = NEGINF; int bk = 0x7fffffff;

  if (c <= CAP) {
    float thr = gm - MARGIN * rnorm[n];
    for (int j = lane; j < c; j += 64) {
      if (cval[n * CAP + j] >= thr) {
        int p = atomicAdd(&lcnts[w], 1);
        lists[w][p] = cand[n * CAP + j];
      }
    }
    int m = lcnts[w];              // same-wave DS ordering guarantees visibility
    for (int j = 0; j < m; ++j) {
      int k = lists[w][j];
      float4 e4 = *(const float4*)(cbl + ((size_t)k << 8) + lane * 4);
      float p = rv4.x * e4.x + rv4.y * e4.y + rv4.z * e4.z + rv4.w * e4.w;
#pragma unroll
      for (int off = 32; off; off >>= 1) p += __shfl_xor(p, off);
      float s = p * invl[k];       // uniform across lanes
      if (s > bv || (s == bv && k < bk)) { bv = s; bk = k; }
    }
  } else {
    // overflow fallback (~never): wave-serial full exact scan
    for (int k = 0; k < 4096; ++k) {
      float4 e4 = *(const float4*)(cbl + ((size_t)k << 8) + lane * 4);
      float p = rv4.x * e4.x + rv4.y * e4.y + rv4.z * e4.z + rv4.w * e4.w;
#pragma unroll
      for (int off = 32; off; off >>= 1) p += __shfl_xor(p, off);
      float s = p * invl[k];
      if (s > bv || (s == bv && k < bk)) { bv = s; bk = k; }
    }
  }
  if (lane == 0) out_idx[(l << 12) + n] = (float)bk;

  // residual update + next-level A split (AS/rnorm/cnt dead at l==3)
  float4 e4 = *(const float4*)(cbl + ((size_t)bk << 8) + lane * 4);
  float4 nv = {rv4.x - e4.x, rv4.y - e4.y, rv4.z - e4.z, rv4.w - e4.w};
  *(float4*)(r + ((size_t)n << 8) + lane * 4) = nv;
  if (l != 3) {
    short4v s4;
    s4[0] = (short)f2bf(nv.x); s4[1] = (short)f2bf(nv.y);
    s4[2] = (short)f2bf(nv.z); s4[3] = (short)f2bf(nv.w);
    *(short4v*)(AS + ((size_t)n << 8) + lane * 4) = s4;
  }
  float sq = nv.x * nv.x + nv.y * nv.y + nv.z * nv.z + nv.w * nv.w;
#pragma unroll
  for (int off = 32; off; off >>= 1) sq += __shfl_xor(sq, off);
  if (lane == 0) {
    ssq[(l << 12) + n] = sq;
    if (l != 3) { rnorm[n] = sqrtf(sq); cnt[n] = 0; }
  }
}

// ---- z_q_st = z - residual_final (blocks 0..1023); qloss (block 1024) ----
__global__ __launch_bounds__(256) void k_writeq_qloss(const float* __restrict__ z,
                                                      const float* __restrict__ r,
                                                      const float* __restrict__ ssq,
                                                      float* __restrict__ out) {
  int tid = threadIdx.x;
  if (blockIdx.x == 1024) {
    __shared__ float wsumq[4];
    float q = 0.f;
    for (int l = 0; l < 4; ++l) {
      float p = 0.f;
#pragma unroll
      for (int i = 0; i < 16; ++i) p += ssq[l * 4096 + i * 256 + tid];
      int lane = tid & 63, w = tid >> 6;
#pragma unroll
      for (int off = 32; off; off >>= 1) p += __shfl_xor(p, off);
      if (lane == 0) wsumq[w] = p;
      __syncthreads();
      float tot = (wsumq[0] + wsumq[1]) + (wsumq[2] + wsumq[3]);
      q += BETA * (tot * (1.0f / (4096.0f * 256.0f)));
      __syncthreads();
    }
    if (tid == 0) out[1048576 + 16384] = q;
    return;
  }
  __shared__ float t[32][33];
  int id = blockIdx.x;
  int b = id >> 8; int rem = id & 255; int ct = rem >> 5; int ht = rem & 31;
  int c0 = ct * 32, h0 = ht * 32;
  int col = tid & 31, row0 = tid >> 5;
#pragma unroll
  for (int p = 0; p < 4; ++p) {
    int row = row0 + p * 8;
    t[row][col] = r[(b * 1024 + h0 + row) * 256 + c0 + col];
  }
  __syncthreads();
#pragma unroll
  for (int p = 0; p < 4; ++p) {
    int row = row0 + p * 8;
    int o = ((b * 256 + c0 + row) << 10) + h0 + col;
    out[o] = z[o] - t[col][row];
  }
}

extern "C" void kernel_launch(void* const* d_in, const int* in_sizes, int n_in,
                              void* d_out, int out_size, void* d_ws, size_t ws_size,
                              hipStream_t stream) {
  const float* z  = (const float*)d_in[0];
  const float* cb = (const float*)d_in[1];
  float* out = (float*)d_out;
  float* ws  = (float*)d_ws;

  unsigned short* AS = (unsigned short*)(ws + OFF_AS);
  unsigned short* BS = (unsigned short*)(ws + OFF_BS);
  float* r     = ws + OFF_R;
  float* inv   = ws + OFF_INV;
  float* pval  = ws + OFF_PV;
  float* rnorm = ws + OFF_RN;
  int*   cnt   = (int*)(ws + OFF_CNT);
  int*   cand  = (int*)(ws + OFF_CAND);
  float* cval  = ws + OFF_CVAL;
  float* ssq   = ws + OFF_SSQ;

  k_prep<<<2560, 256, 0, stream>>>(z, cb, r, AS, rnorm, cnt, inv, BS);
  for (int l = 0; l < 4; ++l) {
    k_gemm_argmax<<<1024, 256, 0, stream>>>(AS, BS + (size_t)l * 4096 * 256,
                                            pval, rnorm, cnt, cand, cval);
    k_refine_update<<<1024, 256, 0, stream>>>(cb, inv, r, pval, rnorm, cnt,
                                              cand, cval, AS, ssq,
                                              out + 1048576, l);
  }
  k_writeq_qloss<<<1025, 256, 0, stream>>>(z, r, ssq, out);
}